// Round 5
// baseline (219.285 us; speedup 1.0000x reference)
//
#include <hip/hip_runtime.h>

// MaskedAttentionLayer B=4,S=2048,E=1024,H=16,HD=64; fp32 io, bf16 MFMA.
// R11: flash_attn widens R10's reuse geometry: block owns FOUR 128-row
// q-tiles {p,7-p,8+p,15-p} (p=0..3), 512 thr / 8 waves, grid 256 = 1
// block/CU (8 waves/CU, same as R10). Wave w owns row-strip w*16 of each
// q-tile. Staged K/V traffic 209.7 -> 121.6 MB (-42%); staging rounds/CU
// nearly halved. Same proven sync skeleton (syncthreads; gl_lds16;
// syncthreads; compute), same swizzles, same per-subtile arithmetic.
// qkv_gemm (R8) and cvt_all unchanged.

typedef __bf16 bf16x8 __attribute__((ext_vector_type(8)));
typedef __bf16 bf16x4 __attribute__((ext_vector_type(4)));
typedef float f32x4 __attribute__((ext_vector_type(4)));
typedef unsigned short us8 __attribute__((ext_vector_type(8)));
typedef unsigned short us4 __attribute__((ext_vector_type(4)));

#define Bb 4
#define Ss 2048
#define Ee 1024
#define Hh 16
#define HD 64

#if __has_builtin(__builtin_amdgcn_exp2f)
#define EXP2(x) __builtin_amdgcn_exp2f(x)
#else
#define EXP2(x) exp2f(x)
#endif

__device__ __forceinline__ unsigned short f2bf(float f) {
  union { float f; unsigned u; } v; v.f = f;
  unsigned u = v.u;
  u += 0x7fffu + ((u >> 16) & 1u);   // RNE
  return (unsigned short)(u >> 16);
}

__device__ __forceinline__ void gl_lds16(const void* g, void* l) {
  __builtin_amdgcn_global_load_lds((const __attribute__((address_space(1))) void*)g,
                                   (__attribute__((address_space(3))) void*)l, 16, 0, 0);
}

// ds_read_b128 with compile-time byte offset; opaque to compiler waitcnt logic.
#define DSR(d, a, o) asm volatile("ds_read_b128 %0, %1 offset:" #o : "=v"(d) : "v"(a))

// one kernel for all fp32->bf16 converts (x, Wq, Wk, Wv)
__global__ __launch_bounds__(256) void cvt_all(const float* __restrict__ x,
                                               const float* __restrict__ wq,
                                               const float* __restrict__ wk,
                                               const float* __restrict__ wv,
                                               unsigned short* __restrict__ xb,
                                               unsigned short* __restrict__ wb) {
  int i = blockIdx.x * 256 + threadIdx.x;   // float4 index, total 2883584
  const float* src; unsigned short* dst; int idx;
  if (i < 2097152)      { src = x;  dst = xb;                idx = i; }
  else if (i < 2359296) { src = wq; dst = wb;                idx = i - 2097152; }
  else if (i < 2621440) { src = wk; dst = wb + 1048576;      idx = i - 2359296; }
  else                  { src = wv; dst = wb + 2 * 1048576;  idx = i - 2621440; }
  float4 f = ((const float4*)src)[idx];
  us4 o = { f2bf(f.x), f2bf(f.y), f2bf(f.z), f2bf(f.w) };
  ((us4*)dst)[idx] = o;
}

// C[m,n] = sum_e X[m,e] W[n,e] + bias[n].  (R8 structure, unchanged, passed)
// 256x256 tile, BK=64, 512 threads = 8 waves, dispersed-quadrant wave map.
// z=0 (Q): [b,h,s,d] scaled by 0.125*log2e.  z=1 (K): [b,h,s,d].  z=2 (V): [b,h,d,s].
__global__ __launch_bounds__(512, 2) void qkv_gemm(const unsigned short* __restrict__ xb,
                                                   const unsigned short* __restrict__ wb_all,
                                                   const float* __restrict__ bq,
                                                   const float* __restrict__ bk,
                                                   const float* __restrict__ bv,
                                                   unsigned short* __restrict__ qkv) {
  const int z = blockIdx.z;
  const unsigned short* wb = wb_all + (size_t)z * (Ee * Ee);
  const float* bias = (z == 0) ? bq : (z == 1) ? bk : bv;
  unsigned short* outb = qkv + (size_t)z * (Bb * Ss * Ee);
  const float osc = (z == 0) ? 0.180336880f : 1.0f;   // 0.125 * log2(e)

  __shared__ unsigned short SMEM[65536];   // 128 KiB: 2 x (A 16384 + B 16384 elems)

  const int t = threadIdx.x;
  const int wave = t >> 6, lane = t & 63, quad = lane >> 4, ln = lane & 15;
  const int wr = wave >> 2, wc = wave & 3;
  const int m0 = blockIdx.x * 256, n0 = blockIdx.y * 256;

  const int r8 = t >> 3;
  const int cs = ((t & 7) ^ (r8 & 7)) * 8;
  const int t8 = t * 8;
  const unsigned short* gA0 = xb + (size_t)(m0 + r8) * Ee + cs;        // A rows 0..127
  const unsigned short* gA1 = gA0 + 128 * Ee;                          // A rows 128..255
  const unsigned short* gB0 = wb + (size_t)(n0 + r8) * Ee + cs;        // B rows 0..127
  const unsigned short* gB1 = gB0 + 128 * Ee;                          // B rows 128..255

  const int swz0 = ((0 * 4 + quad) ^ (ln & 7)) * 16;
  const int swz1 = ((1 * 4 + quad) ^ (ln & 7)) * 16;
  int aA0 = (wr * 64 + ln) * 128 + swz0;
  int aA1 = (wr * 64 + ln) * 128 + swz1;
  int bA0 = 32768 + (wc * 32 + ln) * 128 + swz0;
  int bA1 = 32768 + (wc * 32 + ln) * 128 + swz1;

  f32x4 acc[2][2][4][2] = {};
  bf16x8 af[4][2], bf0[2][2], bf1[2][2];

  // ---- prologue: stage tile 0 into buf0, half order A0,B0,B1,A1 (vmcnt order!)
  gl_lds16(gA0,           &SMEM[t8]);
  gl_lds16(gA0 + 64 * Ee, &SMEM[t8 + 4096]);
  gl_lds16(gB0,           &SMEM[16384 + t8]);
  gl_lds16(gB0 + 64 * Ee, &SMEM[16384 + t8 + 4096]);
  gl_lds16(gB1,           &SMEM[24576 + t8]);
  gl_lds16(gB1 + 64 * Ee, &SMEM[24576 + t8 + 4096]);
  gl_lds16(gA1,           &SMEM[8192 + t8]);
  gl_lds16(gA1 + 64 * Ee, &SMEM[8192 + t8 + 4096]);

#pragma unroll 1
  for (int kt = 0; kt < 15; ++kt) {
    const int sbuf = ((kt & 1) << 15) ^ 32768;   // stage buffer (elems) for tile kt+1
    const int co = (kt + 1) * 64;                // next tile's K-column offset

    // ================ phase 0: C(qa0,qb0); reads A-lo + B-lo; stages A0(kt+1)
    asm volatile("s_waitcnt vmcnt(4)" ::: "memory");
    asm volatile("s_barrier" ::: "memory");
    DSR(af[0][0], aA0, 0);    DSR(af[1][0], aA0, 2048);
    DSR(af[2][0], aA0, 4096); DSR(af[3][0], aA0, 6144);
    DSR(af[0][1], aA1, 0);    DSR(af[1][1], aA1, 2048);
    DSR(af[2][1], aA1, 4096); DSR(af[3][1], aA1, 6144);
    DSR(bf0[0][0], bA0, 0);   DSR(bf0[1][0], bA0, 2048);
    DSR(bf0[0][1], bA1, 0);   DSR(bf0[1][1], bA1, 2048);
    gl_lds16(gA0 + co,           &SMEM[sbuf + t8]);
    gl_lds16(gA0 + co + 64 * Ee, &SMEM[sbuf + t8 + 4096]);
    asm volatile("s_barrier" ::: "memory");
    asm volatile("s_waitcnt lgkmcnt(0)" ::: "memory");
    __builtin_amdgcn_sched_barrier(0);
    __builtin_amdgcn_s_setprio(1);
#pragma unroll
    for (int kk = 0; kk < 2; ++kk)
#pragma unroll
      for (int i = 0; i < 4; ++i)
#pragma unroll
        for (int j = 0; j < 2; ++j)
          acc[0][0][i][j] = __builtin_amdgcn_mfma_f32_16x16x32_bf16(af[i][kk], bf0[j][kk], acc[0][0][i][j], 0, 0, 0);
    __builtin_amdgcn_s_setprio(0);
    __builtin_amdgcn_sched_barrier(0);

    // ================ phase 1: C(qa0,qb1); reads B-hi; stages B0(kt+1)
    asm volatile("s_waitcnt vmcnt(4)" ::: "memory");
    asm volatile("s_barrier" ::: "memory");
    DSR(bf1[0][0], bA0, 16384); DSR(bf1[1][0], bA0, 18432);
    DSR(bf1[0][1], bA1, 16384); DSR(bf1[1][1], bA1, 18432);
    gl_lds16(gB0 + co,           &SMEM[sbuf + 16384 + t8]);
    gl_lds16(gB0 + co + 64 * Ee, &SMEM[sbuf + 16384 + t8 + 4096]);
    asm volatile("s_barrier" ::: "memory");
    asm volatile("s_waitcnt lgkmcnt(0)" ::: "memory");
    __builtin_amdgcn_sched_barrier(0);
    __builtin_amdgcn_s_setprio(1);
#pragma unroll
    for (int kk = 0; kk < 2; ++kk)
#pragma unroll
      for (int i = 0; i < 4; ++i)
#pragma unroll
        for (int j = 0; j < 2; ++j)
          acc[0][1][i][j] = __builtin_amdgcn_mfma_f32_16x16x32_bf16(af[i][kk], bf1[j][kk], acc[0][1][i][j], 0, 0, 0);
    __builtin_amdgcn_s_setprio(0);
    __builtin_amdgcn_sched_barrier(0);

    // ================ phase 2: C(qa1,qb0); reads A-hi; stages B1(kt+1)
    asm volatile("s_waitcnt vmcnt(4)" ::: "memory");
    asm volatile("s_barrier" ::: "memory");
    DSR(af[0][0], aA0, 16384); DSR(af[1][0], aA0, 18432);
    DSR(af[2][0], aA0, 20480); DSR(af[3][0], aA0, 22528);
    DSR(af[0][1], aA1, 16384); DSR(af[1][1], aA1, 18432);
    DSR(af[2][1], aA1, 20480); DSR(af[3][1], aA1, 22528);
    gl_lds16(gB1 + co,           &SMEM[sbuf + 24576 + t8]);
    gl_lds16(gB1 + co + 64 * Ee, &SMEM[sbuf + 24576 + t8 + 4096]);
    asm volatile("s_barrier" ::: "memory");
    asm volatile("s_waitcnt lgkmcnt(0)" ::: "memory");
    __builtin_amdgcn_sched_barrier(0);
    __builtin_amdgcn_s_setprio(1);
#pragma unroll
    for (int kk = 0; kk < 2; ++kk)
#pragma unroll
      for (int i = 0; i < 4; ++i)
#pragma unroll
        for (int j = 0; j < 2; ++j)
          acc[1][0][i][j] = __builtin_amdgcn_mfma_f32_16x16x32_bf16(af[i][kk], bf0[j][kk], acc[1][0][i][j], 0, 0, 0);
    __builtin_amdgcn_s_setprio(0);
    __builtin_amdgcn_sched_barrier(0);

    // ================ phase 3: C(qa1,qb1); no reads; stages A1(kt+1)
    asm volatile("s_barrier" ::: "memory");
    gl_lds16(gA1 + co,           &SMEM[sbuf + 8192 + t8]);
    gl_lds16(gA1 + co + 64 * Ee, &SMEM[sbuf + 8192 + t8 + 4096]);
    asm volatile("s_barrier" ::: "memory");
    __builtin_amdgcn_sched_barrier(0);
    __builtin_amdgcn_s_setprio(1);
#pragma unroll
    for (int kk = 0; kk < 2; ++kk)
#pragma unroll
      for (int i = 0; i < 4; ++i)
#pragma unroll
        for (int j = 0; j < 2; ++j)
          acc[1][1][i][j] = __builtin_amdgcn_mfma_f32_16x16x32_bf16(af[i][kk], bf1[j][kk], acc[1][1][i][j], 0, 0, 0);
    __builtin_amdgcn_s_setprio(0);
    __builtin_amdgcn_sched_barrier(0);

    aA0 ^= 65536; aA1 ^= 65536; bA0 ^= 65536; bA1 ^= 65536;
  }

  // ---- peeled tile 15: only place vmcnt drains to 0 (bases now at buf1)
  {
    asm volatile("s_waitcnt vmcnt(0)" ::: "memory");
    asm volatile("s_barrier" ::: "memory");
    DSR(af[0][0], aA0, 0);    DSR(af[1][0], aA0, 2048);
    DSR(af[2][0], aA0, 4096); DSR(af[3][0], aA0, 6144);
    DSR(af[0][1], aA1, 0);    DSR(af[1][1], aA1, 2048);
    DSR(af[2][1], aA1, 4096); DSR(af[3][1], aA1, 6144);
    DSR(bf0[0][0], bA0, 0);   DSR(bf0[1][0], bA0, 2048);
    DSR(bf0[0][1], bA1, 0);   DSR(bf0[1][1], bA1, 2048);
    DSR(bf1[0][0], bA0, 16384); DSR(bf1[1][0], bA0, 18432);
    DSR(bf1[0][1], bA1, 16384); DSR(bf1[1][1], bA1, 18432);
    asm volatile("s_waitcnt lgkmcnt(0)" ::: "memory");
    __builtin_amdgcn_sched_barrier(0);
#pragma unroll
    for (int kk = 0; kk < 2; ++kk)
#pragma unroll
      for (int i = 0; i < 4; ++i)
#pragma unroll
        for (int j = 0; j < 2; ++j) {
          acc[0][0][i][j] = __builtin_amdgcn_mfma_f32_16x16x32_bf16(af[i][kk], bf0[j][kk], acc[0][0][i][j], 0, 0, 0);
          acc[0][1][i][j] = __builtin_amdgcn_mfma_f32_16x16x32_bf16(af[i][kk], bf1[j][kk], acc[0][1][i][j], 0, 0, 0);
        }
    __builtin_amdgcn_sched_barrier(0);
    DSR(af[0][0], aA0, 16384); DSR(af[1][0], aA0, 18432);
    DSR(af[2][0], aA0, 20480); DSR(af[3][0], aA0, 22528);
    DSR(af[0][1], aA1, 16384); DSR(af[1][1], aA1, 18432);
    DSR(af[2][1], aA1, 20480); DSR(af[3][1], aA1, 22528);
    asm volatile("s_waitcnt lgkmcnt(0)" ::: "memory");
    __builtin_amdgcn_sched_barrier(0);
#pragma unroll
    for (int kk = 0; kk < 2; ++kk)
#pragma unroll
      for (int i = 0; i < 4; ++i)
#pragma unroll
        for (int j = 0; j < 2; ++j) {
          acc[1][0][i][j] = __builtin_amdgcn_mfma_f32_16x16x32_bf16(af[i][kk], bf0[j][kk], acc[1][0][i][j], 0, 0, 0);
          acc[1][1][i][j] = __builtin_amdgcn_mfma_f32_16x16x32_bf16(af[i][kk], bf1[j][kk], acc[1][1][i][j], 0, 0, 0);
        }
    __builtin_amdgcn_sched_barrier(0);
  }

  // ---- epilogue
  float biasj[2][2];
#pragma unroll
  for (int qb = 0; qb < 2; ++qb)
#pragma unroll
    for (int j = 0; j < 2; ++j)
      biasj[qb][j] = bias[n0 + qb * 128 + wc * 32 + j * 16 + ln];

  if (z != 2) {
#pragma unroll
    for (int qa = 0; qa < 2; ++qa)
#pragma unroll
      for (int qb = 0; qb < 2; ++qb)
#pragma unroll
        for (int i = 0; i < 4; ++i)
#pragma unroll
          for (int j = 0; j < 2; ++j)
#pragma unroll
            for (int r = 0; r < 4; ++r) {
              int m = m0 + qa * 128 + wr * 64 + i * 16 + quad * 4 + r;
              int n = n0 + qb * 128 + wc * 32 + j * 16 + ln;
              int b_ = m >> 11, s = m & 2047;
              int h = n >> 6, d = n & 63;
              outb[(((size_t)b_ * Hh + h) * Ss + s) * HD + d] =
                  f2bf((acc[qa][qb][i][j][r] + biasj[qb][j]) * osc);
            }
  } else {
    // V: transpose to [b,h,d,s] through LDS, one 128-row m-half at a time
    for (int qa = 0; qa < 2; ++qa) {
      __syncthreads();
#pragma unroll
      for (int qb = 0; qb < 2; ++qb)
#pragma unroll
        for (int i = 0; i < 4; ++i)
#pragma unroll
          for (int j = 0; j < 2; ++j)
#pragma unroll
            for (int r = 0; r < 4; ++r) {
              int nc = qb * 128 + wc * 32 + j * 16 + ln;
              int mr = wr * 64 + i * 16 + quad * 4 + r;
              SMEM[nc * 136 + mr] = f2bf(acc[qa][qb][i][j][r] + biasj[qb][j]);
            }
      __syncthreads();
      int nr = t >> 1, mh = t & 1;
      int n = n0 + nr, h = n >> 6, d = n & 63;
      int b_ = m0 >> 11;
      int s0 = (m0 & 2047) + qa * 128 + mh * 64;
#pragma unroll
      for (int q = 0; q < 8; ++q) {
        us8 vdat = *(const us8*)&SMEM[nr * 136 + mh * 64 + q * 8];
        *(us8*)&outb[(((size_t)b_ * Hh + h) * HD + d) * Ss + s0 + q * 8] = vdat;
      }
    }
  }
}

// Flash attention, causal, S^T = K Q^T, max-free exp2 softmax.
// R11: grid 256 (64 bh x 4 p); 512 thr / 8 waves, 1 block/CU. Block p owns
// FOUR 128-row q-tiles {p, 7-p, 8+p, 15-p} inside ONE kt loop over 128-col
// K/V blocks (KTB = 16-p); smaller q-tiles reuse the staged K/V. Wave w owns
// row-strip w*16 of each q-tile (subtile half uw = w>>2). Proven skeleton:
// __syncthreads; 4x gl_lds16; __syncthreads; compute (compiler waits).
__global__ __launch_bounds__(512, 2) void flash_attn(const unsigned short* __restrict__ qkv,
                                                     float* __restrict__ out) {
  const int id = blockIdx.x;
  const int bh = id >> 2;
  const int p = id & 3;             // 0..3
  const int b_ = bh >> 4, h = bh & 15;

  const unsigned short* qb  = qkv + (size_t)bh * (Ss * HD);
  const unsigned short* kb  = qkv + (size_t)(64 + bh) * (Ss * HD);
  const unsigned short* vtb = qkv + (size_t)(128 + bh) * (Ss * HD);  // [d][s]

  __shared__ __bf16 Ks[8192];          // [128 kcol][64 d], chunk swizzle c^(row&7)
  __shared__ __bf16 Vt[8192];          // [64 d][128 kk],  chunk swizzle c^(row&7)
  __shared__ __bf16 Ps[8][16][72];     // per-wave P scratch [qrow][kk]

  const int t = threadIdx.x;
  const int wave = t >> 6, lane = t & 63, quad = lane >> 4, ln = lane & 15;
  const int uw = wave >> 2;            // 64-row subtile half within each q-tile

  // staging: K rows rk(+64 2nd call), 8 chunks/row; V rows rv(+32), 16 chunks/row
  const int rk = t >> 3;               // 0..63
  const int ck = ((t & 7) ^ (rk & 7)) * 8;
  const int rv = t >> 4;               // 0..31
  const int cv = ((t & 15) ^ (rv & 7)) * 8;
  const int t8 = t * 8;

  const int qts[4] = { p, 7 - p, 8 + p, 15 - p };
  const int KTB = 16 - p;              // 128-col K/V blocks to stage

  bf16x8 qf[4][2];                     // [qt][ks]
#pragma unroll
  for (int qt = 0; qt < 4; ++qt)
#pragma unroll
    for (int ks = 0; ks < 2; ++ks)
      qf[qt][ks] = *(const bf16x8*)(qb + (size_t)(qts[qt] * 128 + wave * 16 + ln) * HD +
                                    ks * 32 + quad * 8);

  bf16x8 onef;
#pragma unroll
  for (int j = 0; j < 8; ++j) onef[j] = (__bf16)1.0f;

  f32x4 o[4][4] = {};                  // [qt][g]
  f32x4 l4[4] = {};                    // [qt]

#pragma unroll 1
  for (int kt = 0; kt < KTB; ++kt) {
    const unsigned short* kbt = kb + (size_t)kt * (128 * HD);
    const unsigned short* vbt = vtb + kt * 128;
    __syncthreads();
    gl_lds16(kbt + rk * HD + ck,        &Ks[t8]);
    gl_lds16(kbt + (rk + 64) * HD + ck, &Ks[t8 + 4096]);
    gl_lds16(vbt + rv * Ss + cv,        &Vt[t8]);
    gl_lds16(vbt + (rv + 32) * Ss + cv, &Vt[t8 + 4096]);
    __syncthreads();

#pragma unroll
    for (int h2 = 0; h2 < 2; ++h2) {
      const int kb64 = kt * 2 + h2;
#pragma unroll
      for (int qt = 0; qt < 4; ++qt) {
        const int su = 2 * qts[qt] + uw;         // global 64-row subtile index
        if (kb64 > su) continue;                 // fully masked (wave-uniform)
        const int qrow = qts[qt] * 128 + wave * 16 + ln;

        // S^T = K Q^T
        f32x4 s_acc[4] = {};
#pragma unroll
        for (int g = 0; g < 4; ++g)
#pragma unroll
          for (int ks = 0; ks < 2; ++ks) {
            bf16x8 kf = *(const bf16x8*)&Ks[(h2 * 64 + g * 16 + ln) * 64 +
                                            (((ks * 4 + quad) ^ (ln & 7)) * 8)];
            s_acc[g] = __builtin_amdgcn_mfma_f32_16x16x32_bf16(kf, qf[qt][ks], s_acc[g], 0, 0, 0);
          }

        if (kb64 == su) {                        // diagonal 64-col block
          const int k0 = kb64 * 64;
#pragma unroll
          for (int g = 0; g < 4; ++g)
#pragma unroll
            for (int r = 0; r < 4; ++r) {
              int kcol = k0 + g * 16 + quad * 4 + r;
              if (kcol > qrow) s_acc[g][r] = -__builtin_inff();
            }
        }

        // p = exp2(s) (max-free), pack -> Ps
#pragma unroll
        for (int g = 0; g < 4; ++g) {
          bf16x4 pk = { (__bf16)EXP2(s_acc[g][0]), (__bf16)EXP2(s_acc[g][1]),
                        (__bf16)EXP2(s_acc[g][2]), (__bf16)EXP2(s_acc[g][3]) };
          *(bf16x4*)&Ps[wave][ln][g * 16 + quad * 4] = pk;
        }
        bf16x8 pf[2];
#pragma unroll
        for (int ks = 0; ks < 2; ++ks)
          pf[ks] = *(const bf16x8*)&Ps[wave][ln][ks * 32 + quad * 8];

        // l += P @ ones (row sums land in O-row layout)
        l4[qt] = __builtin_amdgcn_mfma_f32_16x16x32_bf16(pf[0], onef, l4[qt], 0, 0, 0);
        l4[qt] = __builtin_amdgcn_mfma_f32_16x16x32_bf16(pf[1], onef, l4[qt], 0, 0, 0);

        // O += P V
#pragma unroll
        for (int g = 0; g < 4; ++g)
#pragma unroll
          for (int ks = 0; ks < 2; ++ks) {
            bf16x8 vf = *(const bf16x8*)&Vt[(g * 16 + ln) * 128 +
                                            (((h2 * 8 + ks * 4 + quad) ^ (ln & 7)) * 8)];
            o[qt][g] = __builtin_amdgcn_mfma_f32_16x16x32_bf16(pf[ks], vf, o[qt][g], 0, 0, 0);
          }
      }
    }
  }

  // epilogue: four q-tiles
#pragma unroll
  for (int qt = 0; qt < 4; ++qt) {
    float linv[4];
#pragma unroll
    for (int r = 0; r < 4; ++r) linv[r] = 1.0f / l4[qt][r];
#pragma unroll
    for (int g = 0; g < 4; ++g)
#pragma unroll
      for (int r = 0; r < 4; ++r) {
        int orow = qts[qt] * 128 + wave * 16 + quad * 4 + r;
        out[((size_t)b_ * Ss + orow) * Ee + h * HD + g * 16 + ln] = o[qt][g][r] * linv[r];
      }
  }
}

extern "C" void kernel_launch(void* const* d_in, const int* in_sizes, int n_in,
                              void* d_out, int out_size, void* d_ws, size_t ws_size,
                              hipStream_t stream) {
  const float* x  = (const float*)d_in[0];
  const float* Wq = (const float*)d_in[1];
  const float* bq = (const float*)d_in[2];
  const float* Wk = (const float*)d_in[3];
  const float* bk = (const float*)d_in[4];
  const float* Wv = (const float*)d_in[5];
  const float* bv = (const float*)d_in[6];
  float* out = (float*)d_out;

  unsigned short* ws  = (unsigned short*)d_ws;
  unsigned short* xb  = ws;                                   // 8388608
  unsigned short* wb  = ws + 8388608;                         // 3 * 1048576
  unsigned short* qkv = ws + 8388608 + 3 * 1048576;           // 3 * 8388608

  cvt_all<<<11264, 256, 0, stream>>>(x, Wq, Wk, Wv, xb, wb);
  qkv_gemm<<<dim3(32, 4, 3), 512, 0, stream>>>(xb, wb, bq, bk, bv, qkv);
  flash_attn<<<256, 512, 0, stream>>>(qkv, out);
}

// Round 6
// 209.079 us; speedup vs baseline: 1.0488x; 1.0488x over previous
//
#include <hip/hip_runtime.h>

// MaskedAttentionLayer B=4,S=2048,E=1024,H=16,HD=64; fp32 io, bf16 MFMA.
// R12: qkv_gemm re-parameterized from 256^2 (R8) to 128^2 tiles to fix
// residency/balance: LDS 128->64 KiB => 2 blocks/CU; grid 384->1536 = 3
// exact rounds (was 1.5 rounds: half the CUs idle 25% of the dispatch).
// Pipeline structure, stage order, vmcnt(4) queue discipline, XOR swizzle
// and asm ds_read are the VERIFIED R8 code with constants halved
// (per-phase load counts identical). flash_attn reverted to R10 (best
// verified total). cvt_all unchanged.

typedef __bf16 bf16x8 __attribute__((ext_vector_type(8)));
typedef __bf16 bf16x4 __attribute__((ext_vector_type(4)));
typedef float f32x4 __attribute__((ext_vector_type(4)));
typedef unsigned short us8 __attribute__((ext_vector_type(8)));
typedef unsigned short us4 __attribute__((ext_vector_type(4)));

#define Bb 4
#define Ss 2048
#define Ee 1024
#define Hh 16
#define HD 64

#if __has_builtin(__builtin_amdgcn_exp2f)
#define EXP2(x) __builtin_amdgcn_exp2f(x)
#else
#define EXP2(x) exp2f(x)
#endif

__device__ __forceinline__ unsigned short f2bf(float f) {
  union { float f; unsigned u; } v; v.f = f;
  unsigned u = v.u;
  u += 0x7fffu + ((u >> 16) & 1u);   // RNE
  return (unsigned short)(u >> 16);
}

__device__ __forceinline__ void gl_lds16(const void* g, void* l) {
  __builtin_amdgcn_global_load_lds((const __attribute__((address_space(1))) void*)g,
                                   (__attribute__((address_space(3))) void*)l, 16, 0, 0);
}

// ds_read_b128 with compile-time byte offset; opaque to compiler waitcnt logic.
#define DSR(d, a, o) asm volatile("ds_read_b128 %0, %1 offset:" #o : "=v"(d) : "v"(a))

// one kernel for all fp32->bf16 converts (x, Wq, Wk, Wv)
__global__ __launch_bounds__(256) void cvt_all(const float* __restrict__ x,
                                               const float* __restrict__ wq,
                                               const float* __restrict__ wk,
                                               const float* __restrict__ wv,
                                               unsigned short* __restrict__ xb,
                                               unsigned short* __restrict__ wb) {
  int i = blockIdx.x * 256 + threadIdx.x;   // float4 index, total 2883584
  const float* src; unsigned short* dst; int idx;
  if (i < 2097152)      { src = x;  dst = xb;                idx = i; }
  else if (i < 2359296) { src = wq; dst = wb;                idx = i - 2097152; }
  else if (i < 2621440) { src = wk; dst = wb + 1048576;      idx = i - 2359296; }
  else                  { src = wv; dst = wb + 2 * 1048576;  idx = i - 2621440; }
  float4 f = ((const float4*)src)[idx];
  us4 o = { f2bf(f.x), f2bf(f.y), f2bf(f.z), f2bf(f.w) };
  ((us4*)dst)[idx] = o;
}

// C[m,n] = sum_e X[m,e] W[n,e] + bias[n].
// 128x128 tile, BK=64, 256 threads = 4 waves, dispersed-quadrant map:
// wave (wr=w>>1, wc=w&1) owns a 32x32 piece of each 64x64 C-quadrant.
// LDS 64 KiB: 2 x (A[128][64] + B[128][64]) bf16; XOR chunk swizzle.
// Per tile: 4 phases {vmcnt(4); bar; asm ds_reads; stage half-tile of kt+1
// (order A0,B0,B1,A1); bar; lgkmcnt(0); setprio + 8 MFMA (kk-outer)}.
// Grid (64,8,3) = 1536 blocks, 2 blocks/CU, 3 exact rounds.
// z=0 (Q): [b,h,s,d] scaled by 0.125*log2e.  z=1 (K): [b,h,s,d].  z=2 (V): [b,h,d,s].
__global__ __launch_bounds__(256, 2) void qkv_gemm(const unsigned short* __restrict__ xb,
                                                   const unsigned short* __restrict__ wb_all,
                                                   const float* __restrict__ bq,
                                                   const float* __restrict__ bk,
                                                   const float* __restrict__ bv,
                                                   unsigned short* __restrict__ qkv) {
  const int z = blockIdx.z;
  const unsigned short* wb = wb_all + (size_t)z * (Ee * Ee);
  const float* bias = (z == 0) ? bq : (z == 1) ? bk : bv;
  unsigned short* outb = qkv + (size_t)z * (Bb * Ss * Ee);
  const float osc = (z == 0) ? 0.180336880f : 1.0f;   // 0.125 * log2(e)

  __shared__ unsigned short SMEM[32768];   // 64 KiB: 2 x (A 8192 + B 8192 elems)

  const int t = threadIdx.x;
  const int wave = t >> 6, lane = t & 63, quad = lane >> 4, ln = lane & 15;
  const int wr = wave >> 1, wc = wave & 1;
  const int m0 = blockIdx.x * 128, n0 = blockIdx.y * 128;

  // staging: thread t loads row r32=t>>3 (+32 for 2nd call), chunk (t&7)^(r32&7),
  // LDS linear dest t*8 elems (both-sides swizzle). 2 calls per 64-row half-tile.
  const int r32 = t >> 3;
  const int cs = ((t & 7) ^ (r32 & 7)) * 8;
  const int t8 = t * 8;
  const unsigned short* gA0 = xb + (size_t)(m0 + r32) * Ee + cs;       // A rows 0..63
  const unsigned short* gA1 = gA0 + 64 * Ee;                           // A rows 64..127
  const unsigned short* gB0 = wb + (size_t)(n0 + r32) * Ee + cs;       // B rows 0..63
  const unsigned short* gB1 = gB0 + 64 * Ee;                           // B rows 64..127

  // asm ds_read byte bases (kk=0,1); hi-quadrant = +8192 B, i/j step = +2048 B
  const int swz0 = ((0 * 4 + quad) ^ (ln & 7)) * 16;
  const int swz1 = ((1 * 4 + quad) ^ (ln & 7)) * 16;
  int aA0 = (wr * 32 + ln) * 128 + swz0;
  int aA1 = (wr * 32 + ln) * 128 + swz1;
  int bA0 = 16384 + (wc * 32 + ln) * 128 + swz0;
  int bA1 = 16384 + (wc * 32 + ln) * 128 + swz1;

  f32x4 acc[2][2][2][2] = {};
  bf16x8 af[2][2], bf0[2][2], bf1[2][2];

  // ---- prologue: stage tile 0 into buf0, half order A0,B0,B1,A1 (vmcnt order!)
  gl_lds16(gA0,           &SMEM[t8]);
  gl_lds16(gA0 + 32 * Ee, &SMEM[t8 + 2048]);
  gl_lds16(gB0,           &SMEM[8192 + t8]);
  gl_lds16(gB0 + 32 * Ee, &SMEM[8192 + t8 + 2048]);
  gl_lds16(gB1,           &SMEM[12288 + t8]);
  gl_lds16(gB1 + 32 * Ee, &SMEM[12288 + t8 + 2048]);
  gl_lds16(gA1,           &SMEM[4096 + t8]);
  gl_lds16(gA1 + 32 * Ee, &SMEM[4096 + t8 + 2048]);

#pragma unroll 1
  for (int kt = 0; kt < 15; ++kt) {
    const int sbuf = ((kt & 1) << 14) ^ 16384;   // stage buffer (elems) for tile kt+1
    const int co = (kt + 1) * 64;                // next tile's K-column offset

    // ================ phase 0: C(qa0,qb0); reads A-lo + B-lo; stages A0(kt+1)
    asm volatile("s_waitcnt vmcnt(4)" ::: "memory");
    asm volatile("s_barrier" ::: "memory");
    DSR(af[0][0], aA0, 0);    DSR(af[1][0], aA0, 2048);
    DSR(af[0][1], aA1, 0);    DSR(af[1][1], aA1, 2048);
    DSR(bf0[0][0], bA0, 0);   DSR(bf0[1][0], bA0, 2048);
    DSR(bf0[0][1], bA1, 0);   DSR(bf0[1][1], bA1, 2048);
    gl_lds16(gA0 + co,           &SMEM[sbuf + t8]);
    gl_lds16(gA0 + co + 32 * Ee, &SMEM[sbuf + t8 + 2048]);
    asm volatile("s_barrier" ::: "memory");
    asm volatile("s_waitcnt lgkmcnt(0)" ::: "memory");
    __builtin_amdgcn_sched_barrier(0);
    __builtin_amdgcn_s_setprio(1);
#pragma unroll
    for (int kk = 0; kk < 2; ++kk)
#pragma unroll
      for (int i = 0; i < 2; ++i)
#pragma unroll
        for (int j = 0; j < 2; ++j)
          acc[0][0][i][j] = __builtin_amdgcn_mfma_f32_16x16x32_bf16(af[i][kk], bf0[j][kk], acc[0][0][i][j], 0, 0, 0);
    __builtin_amdgcn_s_setprio(0);
    __builtin_amdgcn_sched_barrier(0);

    // ================ phase 1: C(qa0,qb1); reads B-hi; stages B0(kt+1)
    asm volatile("s_waitcnt vmcnt(4)" ::: "memory");
    asm volatile("s_barrier" ::: "memory");
    DSR(bf1[0][0], bA0, 8192); DSR(bf1[1][0], bA0, 10240);
    DSR(bf1[0][1], bA1, 8192); DSR(bf1[1][1], bA1, 10240);
    gl_lds16(gB0 + co,           &SMEM[sbuf + 8192 + t8]);
    gl_lds16(gB0 + co + 32 * Ee, &SMEM[sbuf + 8192 + t8 + 2048]);
    asm volatile("s_barrier" ::: "memory");
    asm volatile("s_waitcnt lgkmcnt(0)" ::: "memory");
    __builtin_amdgcn_sched_barrier(0);
    __builtin_amdgcn_s_setprio(1);
#pragma unroll
    for (int kk = 0; kk < 2; ++kk)
#pragma unroll
      for (int i = 0; i < 2; ++i)
#pragma unroll
        for (int j = 0; j < 2; ++j)
          acc[0][1][i][j] = __builtin_amdgcn_mfma_f32_16x16x32_bf16(af[i][kk], bf1[j][kk], acc[0][1][i][j], 0, 0, 0);
    __builtin_amdgcn_s_setprio(0);
    __builtin_amdgcn_sched_barrier(0);

    // ================ phase 2: C(qa1,qb0); reads A-hi; stages B1(kt+1)
    asm volatile("s_waitcnt vmcnt(4)" ::: "memory");
    asm volatile("s_barrier" ::: "memory");
    DSR(af[0][0], aA0, 8192); DSR(af[1][0], aA0, 10240);
    DSR(af[0][1], aA1, 8192); DSR(af[1][1], aA1, 10240);
    gl_lds16(gB1 + co,           &SMEM[sbuf + 12288 + t8]);
    gl_lds16(gB1 + co + 32 * Ee, &SMEM[sbuf + 12288 + t8 + 2048]);
    asm volatile("s_barrier" ::: "memory");
    asm volatile("s_waitcnt lgkmcnt(0)" ::: "memory");
    __builtin_amdgcn_sched_barrier(0);
    __builtin_amdgcn_s_setprio(1);
#pragma unroll
    for (int kk = 0; kk < 2; ++kk)
#pragma unroll
      for (int i = 0; i < 2; ++i)
#pragma unroll
        for (int j = 0; j < 2; ++j)
          acc[1][0][i][j] = __builtin_amdgcn_mfma_f32_16x16x32_bf16(af[i][kk], bf0[j][kk], acc[1][0][i][j], 0, 0, 0);
    __builtin_amdgcn_s_setprio(0);
    __builtin_amdgcn_sched_barrier(0);

    // ================ phase 3: C(qa1,qb1); no reads; stages A1(kt+1)
    asm volatile("s_barrier" ::: "memory");
    gl_lds16(gA1 + co,           &SMEM[sbuf + 4096 + t8]);
    gl_lds16(gA1 + co + 32 * Ee, &SMEM[sbuf + 4096 + t8 + 2048]);
    asm volatile("s_barrier" ::: "memory");
    __builtin_amdgcn_sched_barrier(0);
    __builtin_amdgcn_s_setprio(1);
#pragma unroll
    for (int kk = 0; kk < 2; ++kk)
#pragma unroll
      for (int i = 0; i < 2; ++i)
#pragma unroll
        for (int j = 0; j < 2; ++j)
          acc[1][1][i][j] = __builtin_amdgcn_mfma_f32_16x16x32_bf16(af[i][kk], bf1[j][kk], acc[1][1][i][j], 0, 0, 0);
    __builtin_amdgcn_s_setprio(0);
    __builtin_amdgcn_sched_barrier(0);

    aA0 ^= 32768; aA1 ^= 32768; bA0 ^= 32768; bA1 ^= 32768;
  }

  // ---- peeled tile 15: only place vmcnt drains to 0 (bases now at buf1)
  {
    asm volatile("s_waitcnt vmcnt(0)" ::: "memory");
    asm volatile("s_barrier" ::: "memory");
    DSR(af[0][0], aA0, 0);    DSR(af[1][0], aA0, 2048);
    DSR(af[0][1], aA1, 0);    DSR(af[1][1], aA1, 2048);
    DSR(bf0[0][0], bA0, 0);   DSR(bf0[1][0], bA0, 2048);
    DSR(bf0[0][1], bA1, 0);   DSR(bf0[1][1], bA1, 2048);
    DSR(bf1[0][0], bA0, 8192); DSR(bf1[1][0], bA0, 10240);
    DSR(bf1[0][1], bA1, 8192); DSR(bf1[1][1], bA1, 10240);
    asm volatile("s_waitcnt lgkmcnt(0)" ::: "memory");
    __builtin_amdgcn_sched_barrier(0);
#pragma unroll
    for (int kk = 0; kk < 2; ++kk)
#pragma unroll
      for (int i = 0; i < 2; ++i)
#pragma unroll
        for (int j = 0; j < 2; ++j) {
          acc[0][0][i][j] = __builtin_amdgcn_mfma_f32_16x16x32_bf16(af[i][kk], bf0[j][kk], acc[0][0][i][j], 0, 0, 0);
          acc[0][1][i][j] = __builtin_amdgcn_mfma_f32_16x16x32_bf16(af[i][kk], bf1[j][kk], acc[0][1][i][j], 0, 0, 0);
        }
    __builtin_amdgcn_sched_barrier(0);
    DSR(af[0][0], aA0, 8192); DSR(af[1][0], aA0, 10240);
    DSR(af[0][1], aA1, 8192); DSR(af[1][1], aA1, 10240);
    asm volatile("s_waitcnt lgkmcnt(0)" ::: "memory");
    __builtin_amdgcn_sched_barrier(0);
#pragma unroll
    for (int kk = 0; kk < 2; ++kk)
#pragma unroll
      for (int i = 0; i < 2; ++i)
#pragma unroll
        for (int j = 0; j < 2; ++j) {
          acc[1][0][i][j] = __builtin_amdgcn_mfma_f32_16x16x32_bf16(af[i][kk], bf0[j][kk], acc[1][0][i][j], 0, 0, 0);
          acc[1][1][i][j] = __builtin_amdgcn_mfma_f32_16x16x32_bf16(af[i][kk], bf1[j][kk], acc[1][1][i][j], 0, 0, 0);
        }
    __builtin_amdgcn_sched_barrier(0);
  }

  // ---- epilogue
  float biasj[2][2];
#pragma unroll
  for (int qb = 0; qb < 2; ++qb)
#pragma unroll
    for (int j = 0; j < 2; ++j)
      biasj[qb][j] = bias[n0 + qb * 64 + wc * 32 + j * 16 + ln];

  if (z != 2) {
#pragma unroll
    for (int qa = 0; qa < 2; ++qa)
#pragma unroll
      for (int qb = 0; qb < 2; ++qb)
#pragma unroll
        for (int i = 0; i < 2; ++i)
#pragma unroll
          for (int j = 0; j < 2; ++j)
#pragma unroll
            for (int r = 0; r < 4; ++r) {
              int m = m0 + qa * 64 + wr * 32 + i * 16 + quad * 4 + r;
              int n = n0 + qb * 64 + wc * 32 + j * 16 + ln;
              int b_ = m >> 11, s = m & 2047;
              int h = n >> 6, d = n & 63;
              outb[(((size_t)b_ * Hh + h) * Ss + s) * HD + d] =
                  f2bf((acc[qa][qb][i][j][r] + biasj[qb][j]) * osc);
            }
  } else {
    // V: transpose to [b,h,d,s] through LDS (128x128 fits in one pass)
    __syncthreads();
#pragma unroll
    for (int qa = 0; qa < 2; ++qa)
#pragma unroll
      for (int qb = 0; qb < 2; ++qb)
#pragma unroll
        for (int i = 0; i < 2; ++i)
#pragma unroll
          for (int j = 0; j < 2; ++j)
#pragma unroll
            for (int r = 0; r < 4; ++r) {
              int nc = qb * 64 + wc * 32 + j * 16 + ln;
              int mr = qa * 64 + wr * 32 + i * 16 + quad * 4 + r;
              SMEM[nc * 136 + mr] = f2bf(acc[qa][qb][i][j][r] + biasj[qb][j]);
            }
    __syncthreads();
    int nr = t >> 1, mh = t & 1;
    int n = n0 + nr, h = n >> 6, d = n & 63;
    int b_ = m0 >> 11;
    int s0 = (m0 & 2047) + mh * 64;
#pragma unroll
    for (int q = 0; q < 8; ++q) {
      us8 vdat = *(const us8*)&SMEM[nr * 136 + mh * 64 + q * 8];
      *(us8*)&outb[(((size_t)b_ * Hh + h) * HD + d) * Ss + s0 + q * 8] = vdat;
    }
  }
}

// Flash attention, causal, S^T = K Q^T, max-free exp2 softmax.  (R10, verified)
// grid 512 (64 bh x 8 p); 256 thr / 4 waves. Block p computes BOTH q-tiles
// {15-p, p} inside ONE kt loop over 128-col K/V blocks; small q-tile reuses
// staged K/V. __syncthreads; 8x gl_lds16; __syncthreads; compute.
__global__ __launch_bounds__(256, 2) void flash_attn(const unsigned short* __restrict__ qkv,
                                                     float* __restrict__ out) {
  const int id = blockIdx.x;
  const int bh = id & 63;
  const int p = id >> 6;            // 0..7
  const int b_ = bh >> 4, h = bh & 15;

  const unsigned short* qb  = qkv + (size_t)bh * (Ss * HD);
  const unsigned short* kb  = qkv + (size_t)(64 + bh) * (Ss * HD);
  const unsigned short* vtb = qkv + (size_t)(128 + bh) * (Ss * HD);  // [d][s]

  __shared__ __bf16 Ks[8192];          // [128 kcol][64 d], chunk swizzle c^(row&7)
  __shared__ __bf16 Vt[8192];          // [64 d][128 kk],  chunk swizzle c^(row&7)
  __shared__ __bf16 Ps[4][16][72];     // per-wave P scratch [qrow][kk]

  const int t = threadIdx.x;
  const int wave = t >> 6, lane = t & 63, quad = lane >> 4, ln = lane & 15;

  const int rk = t >> 3;
  const int ck = ((t & 7) ^ (rk & 7)) * 8;
  const int rv = t >> 4;
  const int cv = ((t & 15) ^ (rv & 7)) * 8;
  const int t8 = t * 8;

  const int qts[2] = { 15 - p, p };    // big triangle first; small reuses staging
  const int KTB = qts[0] + 1;          // 128-col blocks to stage... (qtp*128+128)/128

  bf16x8 qf[2][2][2];                  // [qt][u][ks]
#pragma unroll
  for (int qt = 0; qt < 2; ++qt)
#pragma unroll
    for (int u = 0; u < 2; ++u)
#pragma unroll
      for (int ks = 0; ks < 2; ++ks)
        qf[qt][u][ks] = *(const bf16x8*)(qb + (size_t)(qts[qt] * 128 + u * 64 + wave * 16 + ln) * HD +
                                         ks * 32 + quad * 8);

  bf16x8 onef;
#pragma unroll
  for (int j = 0; j < 8; ++j) onef[j] = (__bf16)1.0f;

  f32x4 o[2][2][4] = {};               // [qt][u][g]
  f32x4 l4[2][2] = {};                 // [qt][u]

#pragma unroll 1
  for (int kt = 0; kt < KTB; ++kt) {
    const unsigned short* kbt = kb + (size_t)kt * (128 * HD);
    const unsigned short* vbt = vtb + kt * 128;
    __syncthreads();
    gl_lds16(kbt + rk * HD + ck,        &Ks[t8]);
    gl_lds16(kbt + (rk + 32) * HD + ck, &Ks[t8 + 2048]);
    gl_lds16(kbt + (rk + 64) * HD + ck, &Ks[t8 + 4096]);
    gl_lds16(kbt + (rk + 96) * HD + ck, &Ks[t8 + 6144]);
    gl_lds16(vbt + rv * Ss + cv,        &Vt[t8]);
    gl_lds16(vbt + (rv + 16) * Ss + cv, &Vt[t8 + 2048]);
    gl_lds16(vbt + (rv + 32) * Ss + cv, &Vt[t8 + 4096]);
    gl_lds16(vbt + (rv + 48) * Ss + cv, &Vt[t8 + 6144]);
    __syncthreads();

#pragma unroll
    for (int h2 = 0; h2 < 2; ++h2) {
      const int kb64 = kt * 2 + h2;
#pragma unroll
      for (int qt = 0; qt < 2; ++qt) {
        const int qtp = qts[qt];
#pragma unroll
        for (int u = 0; u < 2; ++u) {
          const int su = 2 * qtp + u;
          if (kb64 > su) continue;               // fully masked subtile
          const int qrow = qtp * 128 + u * 64 + wave * 16 + ln;

          // S^T = K Q^T
          f32x4 s_acc[4] = {};
#pragma unroll
          for (int g = 0; g < 4; ++g)
#pragma unroll
            for (int ks = 0; ks < 2; ++ks) {
              bf16x8 kf = *(const bf16x8*)&Ks[(h2 * 64 + g * 16 + ln) * 64 +
                                              (((ks * 4 + quad) ^ (ln & 7)) * 8)];
              s_acc[g] = __builtin_amdgcn_mfma_f32_16x16x32_bf16(kf, qf[qt][u][ks], s_acc[g], 0, 0, 0);
            }

          if (kb64 == su) {                      // diagonal 64-col block
            const int k0 = kb64 * 64;
#pragma unroll
            for (int g = 0; g < 4; ++g)
#pragma unroll
              for (int r = 0; r < 4; ++r) {
                int kcol = k0 + g * 16 + quad * 4 + r;
                if (kcol > qrow) s_acc[g][r] = -__builtin_inff();
              }
          }

          // p = exp2(s) (max-free), pack -> Ps
#pragma unroll
          for (int g = 0; g < 4; ++g) {
            bf16x4 pk = { (__bf16)EXP2(s_acc[g][0]), (__bf16)EXP2(s_acc[g][1]),
                          (__bf16)EXP2(s_acc[g][2]), (__bf16)EXP2(s_acc[g][3]) };
            *(bf16x4*)&Ps[wave][ln][g * 16 + quad * 4] = pk;
          }
          bf16x8 pf[2];
#pragma unroll
          for (int ks = 0; ks < 2; ++ks)
            pf[ks] = *(const bf16x8*)&Ps[wave][ln][ks * 32 + quad * 8];

          // l += P @ ones (row sums land in O-row layout)
          l4[qt][u] = __builtin_amdgcn_mfma_f32_16x16x32_bf16(pf[0], onef, l4[qt][u], 0, 0, 0);
          l4[qt][u] = __builtin_amdgcn_mfma_f32_16x16x32_bf16(pf[1], onef, l4[qt][u], 0, 0, 0);

          // O += P V
#pragma unroll
          for (int g = 0; g < 4; ++g)
#pragma unroll
            for (int ks = 0; ks < 2; ++ks) {
              bf16x8 vf = *(const bf16x8*)&Vt[(g * 16 + ln) * 128 +
                                              (((h2 * 8 + ks * 4 + quad) ^ (ln & 7)) * 8)];
              o[qt][u][g] = __builtin_amdgcn_mfma_f32_16x16x32_bf16(pf[ks], vf, o[qt][u][g], 0, 0, 0);
            }
        }
      }
    }
  }

  // epilogue: both q-tiles
#pragma unroll
  for (int qt = 0; qt < 2; ++qt)
#pragma unroll
    for (int u = 0; u < 2; ++u) {
      float linv[4];
#pragma unroll
      for (int r = 0; r < 4; ++r) linv[r] = 1.0f / l4[qt][u][r];
#pragma unroll
      for (int g = 0; g < 4; ++g)
#pragma unroll
        for (int r = 0; r < 4; ++r) {
          int orow = qts[qt] * 128 + u * 64 + wave * 16 + quad * 4 + r;
          out[((size_t)b_ * Ss + orow) * Ee + h * HD + g * 16 + ln] = o[qt][u][g][r] * linv[r];
        }
    }
}

extern "C" void kernel_launch(void* const* d_in, const int* in_sizes, int n_in,
                              void* d_out, int out_size, void* d_ws, size_t ws_size,
                              hipStream_t stream) {
  const float* x  = (const float*)d_in[0];
  const float* Wq = (const float*)d_in[1];
  const float* bq = (const float*)d_in[2];
  const float* Wk = (const float*)d_in[3];
  const float* bk = (const float*)d_in[4];
  const float* Wv = (const float*)d_in[5];
  const float* bv = (const float*)d_in[6];
  float* out = (float*)d_out;

  unsigned short* ws  = (unsigned short*)d_ws;
  unsigned short* xb  = ws;                                   // 8388608
  unsigned short* wb  = ws + 8388608;                         // 3 * 1048576
  unsigned short* qkv = ws + 8388608 + 3 * 1048576;           // 3 * 8388608

  cvt_all<<<11264, 256, 0, stream>>>(x, Wq, Wk, Wv, xb, wb);
  qkv_gemm<<<dim3(64, 8, 3), 256, 0, stream>>>(xb, wb, bq, bk, bv, qkv);
  flash_attn<<<512, 256, 0, stream>>>(qkv, out);
}

// Round 7
// 201.194 us; speedup vs baseline: 1.0899x; 1.0392x over previous
//
#include <hip/hip_runtime.h>

// MaskedAttentionLayer B=4,S=2048,E=1024,H=16,HD=64; fp32 io, bf16 MFMA.
// R13: flash_attn reshaped for TLP: 512 thr / 8 waves per block (was 256/4),
// grid 512 -> 16 waves/CU = 4 waves/SIMD (2x). Wave w owns the 16-row strip
// w*16 of each paired q-tile (old (u,wave) -> w=u*4+wave: same rows, same
// tile order, bit-identical math). Staging bytes, sync skeleton, swizzles
// unchanged. qkv_gemm (R12 128^2, 2 blk/CU, 3 rounds) + cvt_all unchanged.

typedef __bf16 bf16x8 __attribute__((ext_vector_type(8)));
typedef __bf16 bf16x4 __attribute__((ext_vector_type(4)));
typedef float f32x4 __attribute__((ext_vector_type(4)));
typedef unsigned short us8 __attribute__((ext_vector_type(8)));
typedef unsigned short us4 __attribute__((ext_vector_type(4)));

#define Bb 4
#define Ss 2048
#define Ee 1024
#define Hh 16
#define HD 64

#if __has_builtin(__builtin_amdgcn_exp2f)
#define EXP2(x) __builtin_amdgcn_exp2f(x)
#else
#define EXP2(x) exp2f(x)
#endif

__device__ __forceinline__ unsigned short f2bf(float f) {
  union { float f; unsigned u; } v; v.f = f;
  unsigned u = v.u;
  u += 0x7fffu + ((u >> 16) & 1u);   // RNE
  return (unsigned short)(u >> 16);
}

__device__ __forceinline__ void gl_lds16(const void* g, void* l) {
  __builtin_amdgcn_global_load_lds((const __attribute__((address_space(1))) void*)g,
                                   (__attribute__((address_space(3))) void*)l, 16, 0, 0);
}

// ds_read_b128 with compile-time byte offset; opaque to compiler waitcnt logic.
#define DSR(d, a, o) asm volatile("ds_read_b128 %0, %1 offset:" #o : "=v"(d) : "v"(a))

// one kernel for all fp32->bf16 converts (x, Wq, Wk, Wv)
__global__ __launch_bounds__(256) void cvt_all(const float* __restrict__ x,
                                               const float* __restrict__ wq,
                                               const float* __restrict__ wk,
                                               const float* __restrict__ wv,
                                               unsigned short* __restrict__ xb,
                                               unsigned short* __restrict__ wb) {
  int i = blockIdx.x * 256 + threadIdx.x;   // float4 index, total 2883584
  const float* src; unsigned short* dst; int idx;
  if (i < 2097152)      { src = x;  dst = xb;                idx = i; }
  else if (i < 2359296) { src = wq; dst = wb;                idx = i - 2097152; }
  else if (i < 2621440) { src = wk; dst = wb + 1048576;      idx = i - 2359296; }
  else                  { src = wv; dst = wb + 2 * 1048576;  idx = i - 2621440; }
  float4 f = ((const float4*)src)[idx];
  us4 o = { f2bf(f.x), f2bf(f.y), f2bf(f.z), f2bf(f.w) };
  ((us4*)dst)[idx] = o;
}

// C[m,n] = sum_e X[m,e] W[n,e] + bias[n].  (R12 structure, verified)
// 128x128 tile, BK=64, 256 threads = 4 waves, dispersed-quadrant map.
// Grid (64,8,3) = 1536 blocks, 2 blocks/CU, 3 exact rounds.
// z=0 (Q): [b,h,s,d] scaled by 0.125*log2e.  z=1 (K): [b,h,s,d].  z=2 (V): [b,h,d,s].
__global__ __launch_bounds__(256, 2) void qkv_gemm(const unsigned short* __restrict__ xb,
                                                   const unsigned short* __restrict__ wb_all,
                                                   const float* __restrict__ bq,
                                                   const float* __restrict__ bk,
                                                   const float* __restrict__ bv,
                                                   unsigned short* __restrict__ qkv) {
  const int z = blockIdx.z;
  const unsigned short* wb = wb_all + (size_t)z * (Ee * Ee);
  const float* bias = (z == 0) ? bq : (z == 1) ? bk : bv;
  unsigned short* outb = qkv + (size_t)z * (Bb * Ss * Ee);
  const float osc = (z == 0) ? 0.180336880f : 1.0f;   // 0.125 * log2(e)

  __shared__ unsigned short SMEM[32768];   // 64 KiB: 2 x (A 8192 + B 8192 elems)

  const int t = threadIdx.x;
  const int wave = t >> 6, lane = t & 63, quad = lane >> 4, ln = lane & 15;
  const int wr = wave >> 1, wc = wave & 1;
  const int m0 = blockIdx.x * 128, n0 = blockIdx.y * 128;

  const int r32 = t >> 3;
  const int cs = ((t & 7) ^ (r32 & 7)) * 8;
  const int t8 = t * 8;
  const unsigned short* gA0 = xb + (size_t)(m0 + r32) * Ee + cs;       // A rows 0..63
  const unsigned short* gA1 = gA0 + 64 * Ee;                           // A rows 64..127
  const unsigned short* gB0 = wb + (size_t)(n0 + r32) * Ee + cs;       // B rows 0..63
  const unsigned short* gB1 = gB0 + 64 * Ee;                           // B rows 64..127

  const int swz0 = ((0 * 4 + quad) ^ (ln & 7)) * 16;
  const int swz1 = ((1 * 4 + quad) ^ (ln & 7)) * 16;
  int aA0 = (wr * 32 + ln) * 128 + swz0;
  int aA1 = (wr * 32 + ln) * 128 + swz1;
  int bA0 = 16384 + (wc * 32 + ln) * 128 + swz0;
  int bA1 = 16384 + (wc * 32 + ln) * 128 + swz1;

  f32x4 acc[2][2][2][2] = {};
  bf16x8 af[2][2], bf0[2][2], bf1[2][2];

  // ---- prologue: stage tile 0 into buf0, half order A0,B0,B1,A1 (vmcnt order!)
  gl_lds16(gA0,           &SMEM[t8]);
  gl_lds16(gA0 + 32 * Ee, &SMEM[t8 + 2048]);
  gl_lds16(gB0,           &SMEM[8192 + t8]);
  gl_lds16(gB0 + 32 * Ee, &SMEM[8192 + t8 + 2048]);
  gl_lds16(gB1,           &SMEM[12288 + t8]);
  gl_lds16(gB1 + 32 * Ee, &SMEM[12288 + t8 + 2048]);
  gl_lds16(gA1,           &SMEM[4096 + t8]);
  gl_lds16(gA1 + 32 * Ee, &SMEM[4096 + t8 + 2048]);

#pragma unroll 1
  for (int kt = 0; kt < 15; ++kt) {
    const int sbuf = ((kt & 1) << 14) ^ 16384;   // stage buffer (elems) for tile kt+1
    const int co = (kt + 1) * 64;                // next tile's K-column offset

    // ================ phase 0: C(qa0,qb0); reads A-lo + B-lo; stages A0(kt+1)
    asm volatile("s_waitcnt vmcnt(4)" ::: "memory");
    asm volatile("s_barrier" ::: "memory");
    DSR(af[0][0], aA0, 0);    DSR(af[1][0], aA0, 2048);
    DSR(af[0][1], aA1, 0);    DSR(af[1][1], aA1, 2048);
    DSR(bf0[0][0], bA0, 0);   DSR(bf0[1][0], bA0, 2048);
    DSR(bf0[0][1], bA1, 0);   DSR(bf0[1][1], bA1, 2048);
    gl_lds16(gA0 + co,           &SMEM[sbuf + t8]);
    gl_lds16(gA0 + co + 32 * Ee, &SMEM[sbuf + t8 + 2048]);
    asm volatile("s_barrier" ::: "memory");
    asm volatile("s_waitcnt lgkmcnt(0)" ::: "memory");
    __builtin_amdgcn_sched_barrier(0);
    __builtin_amdgcn_s_setprio(1);
#pragma unroll
    for (int kk = 0; kk < 2; ++kk)
#pragma unroll
      for (int i = 0; i < 2; ++i)
#pragma unroll
        for (int j = 0; j < 2; ++j)
          acc[0][0][i][j] = __builtin_amdgcn_mfma_f32_16x16x32_bf16(af[i][kk], bf0[j][kk], acc[0][0][i][j], 0, 0, 0);
    __builtin_amdgcn_s_setprio(0);
    __builtin_amdgcn_sched_barrier(0);

    // ================ phase 1: C(qa0,qb1); reads B-hi; stages B0(kt+1)
    asm volatile("s_waitcnt vmcnt(4)" ::: "memory");
    asm volatile("s_barrier" ::: "memory");
    DSR(bf1[0][0], bA0, 8192); DSR(bf1[1][0], bA0, 10240);
    DSR(bf1[0][1], bA1, 8192); DSR(bf1[1][1], bA1, 10240);
    gl_lds16(gB0 + co,           &SMEM[sbuf + 8192 + t8]);
    gl_lds16(gB0 + co + 32 * Ee, &SMEM[sbuf + 8192 + t8 + 2048]);
    asm volatile("s_barrier" ::: "memory");
    asm volatile("s_waitcnt lgkmcnt(0)" ::: "memory");
    __builtin_amdgcn_sched_barrier(0);
    __builtin_amdgcn_s_setprio(1);
#pragma unroll
    for (int kk = 0; kk < 2; ++kk)
#pragma unroll
      for (int i = 0; i < 2; ++i)
#pragma unroll
        for (int j = 0; j < 2; ++j)
          acc[0][1][i][j] = __builtin_amdgcn_mfma_f32_16x16x32_bf16(af[i][kk], bf1[j][kk], acc[0][1][i][j], 0, 0, 0);
    __builtin_amdgcn_s_setprio(0);
    __builtin_amdgcn_sched_barrier(0);

    // ================ phase 2: C(qa1,qb0); reads A-hi; stages B1(kt+1)
    asm volatile("s_waitcnt vmcnt(4)" ::: "memory");
    asm volatile("s_barrier" ::: "memory");
    DSR(af[0][0], aA0, 8192); DSR(af[1][0], aA0, 10240);
    DSR(af[0][1], aA1, 8192); DSR(af[1][1], aA1, 10240);
    gl_lds16(gB1 + co,           &SMEM[sbuf + 12288 + t8]);
    gl_lds16(gB1 + co + 32 * Ee, &SMEM[sbuf + 12288 + t8 + 2048]);
    asm volatile("s_barrier" ::: "memory");
    asm volatile("s_waitcnt lgkmcnt(0)" ::: "memory");
    __builtin_amdgcn_sched_barrier(0);
    __builtin_amdgcn_s_setprio(1);
#pragma unroll
    for (int kk = 0; kk < 2; ++kk)
#pragma unroll
      for (int i = 0; i < 2; ++i)
#pragma unroll
        for (int j = 0; j < 2; ++j)
          acc[1][0][i][j] = __builtin_amdgcn_mfma_f32_16x16x32_bf16(af[i][kk], bf0[j][kk], acc[1][0][i][j], 0, 0, 0);
    __builtin_amdgcn_s_setprio(0);
    __builtin_amdgcn_sched_barrier(0);

    // ================ phase 3: C(qa1,qb1); no reads; stages A1(kt+1)
    asm volatile("s_barrier" ::: "memory");
    gl_lds16(gA1 + co,           &SMEM[sbuf + 4096 + t8]);
    gl_lds16(gA1 + co + 32 * Ee, &SMEM[sbuf + 4096 + t8 + 2048]);
    asm volatile("s_barrier" ::: "memory");
    __builtin_amdgcn_sched_barrier(0);
    __builtin_amdgcn_s_setprio(1);
#pragma unroll
    for (int kk = 0; kk < 2; ++kk)
#pragma unroll
      for (int i = 0; i < 2; ++i)
#pragma unroll
        for (int j = 0; j < 2; ++j)
          acc[1][1][i][j] = __builtin_amdgcn_mfma_f32_16x16x32_bf16(af[i][kk], bf1[j][kk], acc[1][1][i][j], 0, 0, 0);
    __builtin_amdgcn_s_setprio(0);
    __builtin_amdgcn_sched_barrier(0);

    aA0 ^= 32768; aA1 ^= 32768; bA0 ^= 32768; bA1 ^= 32768;
  }

  // ---- peeled tile 15: only place vmcnt drains to 0 (bases now at buf1)
  {
    asm volatile("s_waitcnt vmcnt(0)" ::: "memory");
    asm volatile("s_barrier" ::: "memory");
    DSR(af[0][0], aA0, 0);    DSR(af[1][0], aA0, 2048);
    DSR(af[0][1], aA1, 0);    DSR(af[1][1], aA1, 2048);
    DSR(bf0[0][0], bA0, 0);   DSR(bf0[1][0], bA0, 2048);
    DSR(bf0[0][1], bA1, 0);   DSR(bf0[1][1], bA1, 2048);
    DSR(bf1[0][0], bA0, 8192); DSR(bf1[1][0], bA0, 10240);
    DSR(bf1[0][1], bA1, 8192); DSR(bf1[1][1], bA1, 10240);
    asm volatile("s_waitcnt lgkmcnt(0)" ::: "memory");
    __builtin_amdgcn_sched_barrier(0);
#pragma unroll
    for (int kk = 0; kk < 2; ++kk)
#pragma unroll
      for (int i = 0; i < 2; ++i)
#pragma unroll
        for (int j = 0; j < 2; ++j) {
          acc[0][0][i][j] = __builtin_amdgcn_mfma_f32_16x16x32_bf16(af[i][kk], bf0[j][kk], acc[0][0][i][j], 0, 0, 0);
          acc[0][1][i][j] = __builtin_amdgcn_mfma_f32_16x16x32_bf16(af[i][kk], bf1[j][kk], acc[0][1][i][j], 0, 0, 0);
        }
    __builtin_amdgcn_sched_barrier(0);
    DSR(af[0][0], aA0, 8192); DSR(af[1][0], aA0, 10240);
    DSR(af[0][1], aA1, 8192); DSR(af[1][1], aA1, 10240);
    asm volatile("s_waitcnt lgkmcnt(0)" ::: "memory");
    __builtin_amdgcn_sched_barrier(0);
#pragma unroll
    for (int kk = 0; kk < 2; ++kk)
#pragma unroll
      for (int i = 0; i < 2; ++i)
#pragma unroll
        for (int j = 0; j < 2; ++j) {
          acc[1][0][i][j] = __builtin_amdgcn_mfma_f32_16x16x32_bf16(af[i][kk], bf0[j][kk], acc[1][0][i][j], 0, 0, 0);
          acc[1][1][i][j] = __builtin_amdgcn_mfma_f32_16x16x32_bf16(af[i][kk], bf1[j][kk], acc[1][1][i][j], 0, 0, 0);
        }
    __builtin_amdgcn_sched_barrier(0);
  }

  // ---- epilogue
  float biasj[2][2];
#pragma unroll
  for (int qb = 0; qb < 2; ++qb)
#pragma unroll
    for (int j = 0; j < 2; ++j)
      biasj[qb][j] = bias[n0 + qb * 64 + wc * 32 + j * 16 + ln];

  if (z != 2) {
#pragma unroll
    for (int qa = 0; qa < 2; ++qa)
#pragma unroll
      for (int qb = 0; qb < 2; ++qb)
#pragma unroll
        for (int i = 0; i < 2; ++i)
#pragma unroll
          for (int j = 0; j < 2; ++j)
#pragma unroll
            for (int r = 0; r < 4; ++r) {
              int m = m0 + qa * 64 + wr * 32 + i * 16 + quad * 4 + r;
              int n = n0 + qb * 64 + wc * 32 + j * 16 + ln;
              int b_ = m >> 11, s = m & 2047;
              int h = n >> 6, d = n & 63;
              outb[(((size_t)b_ * Hh + h) * Ss + s) * HD + d] =
                  f2bf((acc[qa][qb][i][j][r] + biasj[qb][j]) * osc);
            }
  } else {
    // V: transpose to [b,h,d,s] through LDS (128x128 fits in one pass)
    __syncthreads();
#pragma unroll
    for (int qa = 0; qa < 2; ++qa)
#pragma unroll
      for (int qb = 0; qb < 2; ++qb)
#pragma unroll
        for (int i = 0; i < 2; ++i)
#pragma unroll
          for (int j = 0; j < 2; ++j)
#pragma unroll
            for (int r = 0; r < 4; ++r) {
              int nc = qb * 64 + wc * 32 + j * 16 + ln;
              int mr = qa * 64 + wr * 32 + i * 16 + quad * 4 + r;
              SMEM[nc * 136 + mr] = f2bf(acc[qa][qb][i][j][r] + biasj[qb][j]);
            }
    __syncthreads();
    int nr = t >> 1, mh = t & 1;
    int n = n0 + nr, h = n >> 6, d = n & 63;
    int b_ = m0 >> 11;
    int s0 = (m0 & 2047) + mh * 64;
#pragma unroll
    for (int q = 0; q < 8; ++q) {
      us8 vdat = *(const us8*)&SMEM[nr * 136 + mh * 64 + q * 8];
      *(us8*)&outb[(((size_t)b_ * Hh + h) * HD + d) * Ss + s0 + q * 8] = vdat;
    }
  }
}

// Flash attention, causal, S^T = K Q^T, max-free exp2 softmax.
// R13: grid 512 (64 bh x 8 p); 512 thr / 8 waves -> 16 waves/CU (4/SIMD).
// Block p computes BOTH q-tiles {15-p, p} inside ONE kt loop over 128-col
// K/V blocks; wave w owns 16-row strip w*16 of each q-tile (same rows and
// tile order as R12's (u,wave) decomposition -> bit-identical math).
// __syncthreads; 4x gl_lds16; __syncthreads; compute.
__global__ __launch_bounds__(512, 2) void flash_attn(const unsigned short* __restrict__ qkv,
                                                     float* __restrict__ out) {
  const int id = blockIdx.x;
  const int bh = id & 63;
  const int p = id >> 6;            // 0..7
  const int b_ = bh >> 4, h = bh & 15;

  const unsigned short* qb  = qkv + (size_t)bh * (Ss * HD);
  const unsigned short* kb  = qkv + (size_t)(64 + bh) * (Ss * HD);
  const unsigned short* vtb = qkv + (size_t)(128 + bh) * (Ss * HD);  // [d][s]

  __shared__ __bf16 Ks[8192];          // [128 kcol][64 d], chunk swizzle c^(row&7)
  __shared__ __bf16 Vt[8192];          // [64 d][128 kk],  chunk swizzle c^(row&7)
  __shared__ __bf16 Ps[8][16][72];     // per-wave P scratch [qrow][kk]

  const int t = threadIdx.x;
  const int wave = t >> 6, lane = t & 63, quad = lane >> 4, ln = lane & 15;
  const int uw = wave >> 2;            // 64-row subtile half within each q-tile

  // staging (512 thr): K rows rk (+64 2nd call), 8 chunks/row;
  // V rows rv (+32 2nd call), 16 chunks/row.
  const int rk = t >> 3;               // 0..63
  const int ck = ((t & 7) ^ (rk & 7)) * 8;
  const int rv = t >> 4;               // 0..31
  const int cv = ((t & 15) ^ (rv & 7)) * 8;
  const int t8 = t * 8;

  const int qts[2] = { 15 - p, p };    // big triangle first; small reuses staging
  const int KTB = qts[0] + 1;          // 128-col blocks to stage

  bf16x8 qf[2][2];                     // [qt][ks]
#pragma unroll
  for (int qt = 0; qt < 2; ++qt)
#pragma unroll
    for (int ks = 0; ks < 2; ++ks)
      qf[qt][ks] = *(const bf16x8*)(qb + (size_t)(qts[qt] * 128 + wave * 16 + ln) * HD +
                                    ks * 32 + quad * 8);

  bf16x8 onef;
#pragma unroll
  for (int j = 0; j < 8; ++j) onef[j] = (__bf16)1.0f;

  f32x4 o[2][4] = {};                  // [qt][g]
  f32x4 l4[2] = {};                    // [qt]

#pragma unroll 1
  for (int kt = 0; kt < KTB; ++kt) {
    const unsigned short* kbt = kb + (size_t)kt * (128 * HD);
    const unsigned short* vbt = vtb + kt * 128;
    __syncthreads();
    gl_lds16(kbt + rk * HD + ck,        &Ks[t8]);
    gl_lds16(kbt + (rk + 64) * HD + ck, &Ks[t8 + 4096]);
    gl_lds16(vbt + rv * Ss + cv,        &Vt[t8]);
    gl_lds16(vbt + (rv + 32) * Ss + cv, &Vt[t8 + 4096]);
    __syncthreads();

#pragma unroll
    for (int h2 = 0; h2 < 2; ++h2) {
      const int kb64 = kt * 2 + h2;
#pragma unroll
      for (int qt = 0; qt < 2; ++qt) {
        const int qtp = qts[qt];
        const int su = 2 * qtp + uw;             // this wave's 64-row subtile index
        if (kb64 > su) continue;                 // fully masked (wave-uniform)
        const int qrow = qtp * 128 + wave * 16 + ln;

        // S^T = K Q^T
        f32x4 s_acc[4] = {};
#pragma unroll
        for (int g = 0; g < 4; ++g)
#pragma unroll
          for (int ks = 0; ks < 2; ++ks) {
            bf16x8 kf = *(const bf16x8*)&Ks[(h2 * 64 + g * 16 + ln) * 64 +
                                            (((ks * 4 + quad) ^ (ln & 7)) * 8)];
            s_acc[g] = __builtin_amdgcn_mfma_f32_16x16x32_bf16(kf, qf[qt][ks], s_acc[g], 0, 0, 0);
          }

        if (kb64 == su) {                        // diagonal 64-col block
          const int k0 = kb64 * 64;
#pragma unroll
          for (int g = 0; g < 4; ++g)
#pragma unroll
            for (int r = 0; r < 4; ++r) {
              int kcol = k0 + g * 16 + quad * 4 + r;
              if (kcol > qrow) s_acc[g][r] = -__builtin_inff();
            }
        }

        // p = exp2(s) (max-free), pack -> Ps
#pragma unroll
        for (int g = 0; g < 4; ++g) {
          bf16x4 pk = { (__bf16)EXP2(s_acc[g][0]), (__bf16)EXP2(s_acc[g][1]),
                        (__bf16)EXP2(s_acc[g][2]), (__bf16)EXP2(s_acc[g][3]) };
          *(bf16x4*)&Ps[wave][ln][g * 16 + quad * 4] = pk;
        }
        bf16x8 pf[2];
#pragma unroll
        for (int ks = 0; ks < 2; ++ks)
          pf[ks] = *(const bf16x8*)&Ps[wave][ln][ks * 32 + quad * 8];

        // l += P @ ones (row sums land in O-row layout)
        l4[qt] = __builtin_amdgcn_mfma_f32_16x16x32_bf16(pf[0], onef, l4[qt], 0, 0, 0);
        l4[qt] = __builtin_amdgcn_mfma_f32_16x16x32_bf16(pf[1], onef, l4[qt], 0, 0, 0);

        // O += P V
#pragma unroll
        for (int g = 0; g < 4; ++g)
#pragma unroll
          for (int ks = 0; ks < 2; ++ks) {
            bf16x8 vf = *(const bf16x8*)&Vt[(g * 16 + ln) * 128 +
                                            (((h2 * 8 + ks * 4 + quad) ^ (ln & 7)) * 8)];
            o[qt][g] = __builtin_amdgcn_mfma_f32_16x16x32_bf16(pf[ks], vf, o[qt][g], 0, 0, 0);
          }
      }
    }
  }

  // epilogue: both q-tiles
#pragma unroll
  for (int qt = 0; qt < 2; ++qt) {
    float linv[4];
#pragma unroll
    for (int r = 0; r < 4; ++r) linv[r] = 1.0f / l4[qt][r];
#pragma unroll
    for (int g = 0; g < 4; ++g)
#pragma unroll
      for (int r = 0; r < 4; ++r) {
        int orow = qts[qt] * 128 + wave * 16 + quad * 4 + r;
        out[((size_t)b_ * Ss + orow) * Ee + h * HD + g * 16 + ln] = o[qt][g][r] * linv[r];
      }
  }
}

extern "C" void kernel_launch(void* const* d_in, const int* in_sizes, int n_in,
                              void* d_out, int out_size, void* d_ws, size_t ws_size,
                              hipStream_t stream) {
  const float* x  = (const float*)d_in[0];
  const float* Wq = (const float*)d_in[1];
  const float* bq = (const float*)d_in[2];
  const float* Wk = (const float*)d_in[3];
  const float* bk = (const float*)d_in[4];
  const float* Wv = (const float*)d_in[5];
  const float* bv = (const float*)d_in[6];
  float* out = (float*)d_out;

  unsigned short* ws  = (unsigned short*)d_ws;
  unsigned short* xb  = ws;                                   // 8388608
  unsigned short* wb  = ws + 8388608;                         // 3 * 1048576
  unsigned short* qkv = ws + 8388608 + 3 * 1048576;           // 3 * 8388608

  cvt_all<<<11264, 256, 0, stream>>>(x, Wq, Wk, Wv, xb, wb);
  qkv_gemm<<<dim3(64, 8, 3), 256, 0, stream>>>(xb, wb, bq, bk, bv, qkv);
  flash_attn<<<512, 512, 0, stream>>>(qkv, out);
}